// Round 4
// baseline (269.002 us; speedup 1.0000x reference)
//
#include <hip/hip_runtime.h>
#include <math.h>

#ifndef M_PI
#define M_PI 3.14159265358979323846
#endif

#define B_ 8
#define S_ 197
#define E_ 384
#define H_ 6
#define D_ 64
#define N_ (B_*S_)          // 1576
#define EN ((size_t)E_*N_)  // 605184
#define NBLK_RED 591        // EN / 1024 exactly

// ---------------------------------------------------------------------------
// Kernel 1: adder 1x1 partials, split-K over ci (4 chunks of 96).
// P[z][co][n] = sum_{ci in chunk} |x2d[ci][n] - w[co][ci]|,  z = 4p + c.
// Tile 64co x 64n, thread = 4co x 4n.  grid (6, 25, 12) block 256.
// Double-buffered LDS, one barrier per 16-ci step.
// ---------------------------------------------------------------------------
__global__ __launch_bounds__(256) void k_adder(
    const float* __restrict__ x,
    const float* __restrict__ wq, const float* __restrict__ wk,
    const float* __restrict__ wv,
    float* __restrict__ P)
{
  const int z = blockIdx.z;
  const int p = z >> 2, c = z & 3;
  const float* __restrict__ w = (p == 0) ? wq : (p == 1) ? wk : wv;
  const int co0 = blockIdx.x * 64;
  const int n0  = blockIdx.y * 64;
  const int cib = c * 96;

  __shared__ float Xs[2][16][68];   // [buf][ci_local][n_local]
  __shared__ float Ws[2][16][68];   // [buf][ci_local][co_local] (transposed)

  const int tid = threadIdx.x;
  const int tx = tid & 15;          // n direction (4 cols)
  const int ty = tid >> 4;          // co direction (4 rows)

  const int xr = tid >> 4, xc = (tid & 15) * 4;   // X stage: [16][64] float4
  const int wr = tid >> 2, wc = (tid & 3) * 4;    // W stage: 64co x 16ci float4

  const bool xok = (n0 + xc + 3) < N_;            // full float4 or none
  const float* xg = x + (size_t)(cib + xr) * N_ + n0 + xc;
  const float* wg = w + (size_t)(co0 + wr) * E_ + cib + wc;

  float4 xv = xok ? *(const float4*)xg : make_float4(0.f, 0.f, 0.f, 0.f);
  float4 wv4 = *(const float4*)wg;

  float acc[4][4];
  #pragma unroll
  for (int i = 0; i < 4; ++i)
    #pragma unroll
    for (int j = 0; j < 4; ++j) acc[i][j] = 0.f;

  #pragma unroll 1
  for (int t = 0; t < 6; ++t) {
    const int buf = t & 1;
    *(float4*)(&Xs[buf][xr][xc]) = xv;
    Ws[buf][wc + 0][wr] = wv4.x; Ws[buf][wc + 1][wr] = wv4.y;
    Ws[buf][wc + 2][wr] = wv4.z; Ws[buf][wc + 3][wr] = wv4.w;
    __syncthreads();
    if (t < 5) {
      xg += (size_t)16 * N_;
      wg += 16;
      xv = xok ? *(const float4*)xg : make_float4(0.f, 0.f, 0.f, 0.f);
      wv4 = *(const float4*)wg;
    }
    #pragma unroll
    for (int cc = 0; cc < 16; ++cc) {
      float4 a = *(const float4*)(&Xs[buf][cc][tx * 4]);
      float4 b = *(const float4*)(&Ws[buf][cc][ty * 4]);
      float xa[4] = {a.x, a.y, a.z, a.w};
      float wa[4] = {b.x, b.y, b.z, b.w};
      #pragma unroll
      for (int i = 0; i < 4; ++i)
        #pragma unroll
        for (int j = 0; j < 4; ++j)
          acc[i][j] += fabsf(xa[j] - wa[i]);
    }
  }

  if ((n0 + tx * 4 + 3) < N_) {
    #pragma unroll
    for (int i = 0; i < 4; ++i) {
      int co = co0 + ty * 4 + i;
      float4 yv = make_float4(acc[i][0], acc[i][1], acc[i][2], acc[i][3]);
      *(float4*)(P + (size_t)z * EN + (size_t)co * N_ + n0 + tx * 4) = yv;
    }
  }
}

// ---------------------------------------------------------------------------
// Kernel 2: reduce split-K partials in place: Y(=slot 4p) = -(P0+P1+P2+P3),
// plus per-block (sum, sumsq) partials for LN-all.  grid (591, 3) block 256.
// ---------------------------------------------------------------------------
__global__ __launch_bounds__(256) void k_reduceY(
    float* __restrict__ wsbuf, float* __restrict__ partials)
{
  const int p = blockIdx.y;
  float* P0 = wsbuf + (size_t)(4 * p) * EN;
  const int tid = threadIdx.x;
  size_t i = ((size_t)blockIdx.x * 256 + tid) * 4;
  float4 a = *(const float4*)(P0 + i);
  float4 b = *(const float4*)(P0 + EN + i);
  float4 cc = *(const float4*)(P0 + 2 * EN + i);
  float4 d = *(const float4*)(P0 + 3 * EN + i);
  float4 y;
  y.x = -(a.x + b.x + cc.x + d.x);
  y.y = -(a.y + b.y + cc.y + d.y);
  y.z = -(a.z + b.z + cc.z + d.z);
  y.w = -(a.w + b.w + cc.w + d.w);
  *(float4*)(P0 + i) = y;
  float s1 = y.x + y.y + y.z + y.w;
  float s2 = y.x * y.x + y.y * y.y + y.z * y.z + y.w * y.w;
  #pragma unroll
  for (int off = 32; off > 0; off >>= 1) {
    s1 += __shfl_down(s1, off);
    s2 += __shfl_down(s2, off);
  }
  __shared__ float red[8];
  int wid = tid >> 6, lane = tid & 63;
  if (lane == 0) { red[wid * 2] = s1; red[wid * 2 + 1] = s2; }
  __syncthreads();
  if (tid == 0) {
    float t1 = red[0] + red[2] + red[4] + red[6];
    float t2 = red[1] + red[3] + red[5] + red[7];
    partials[((size_t)p * NBLK_RED + blockIdx.x) * 2 + 0] = t1;
    partials[((size_t)p * NBLK_RED + blockIdx.x) * 2 + 1] = t2;
  }
}

// ---------------------------------------------------------------------------
// Kernel 3: reduce partials -> (mean, rstd) per projection.  grid(3) block 256
// ---------------------------------------------------------------------------
__global__ __launch_bounds__(256) void k_stats(
    const float* __restrict__ partials, float* __restrict__ stats)
{
  const int p = blockIdx.x;
  const int tid = threadIdx.x;
  float s1 = 0.f, s2 = 0.f;
  for (int i = tid; i < NBLK_RED; i += 256) {
    s1 += partials[((size_t)p * NBLK_RED + i) * 2 + 0];
    s2 += partials[((size_t)p * NBLK_RED + i) * 2 + 1];
  }
  #pragma unroll
  for (int off = 32; off > 0; off >>= 1) {
    s1 += __shfl_down(s1, off);
    s2 += __shfl_down(s2, off);
  }
  __shared__ float red[8];
  int wid = tid >> 6, lane = tid & 63;
  if (lane == 0) { red[wid * 2] = s1; red[wid * 2 + 1] = s2; }
  __syncthreads();
  if (tid == 0) {
    float S1 = red[0] + red[2] + red[4] + red[6];
    float S2 = red[1] + red[3] + red[5] + red[7];
    float mean = S1 / (float)EN;
    float var = S2 / (float)EN - mean * mean;
    stats[p * 2 + 0] = mean;
    stats[p * 2 + 1] = rsqrtf(var + 1e-5f);
  }
}

// ---------------------------------------------------------------------------
// Kernel 4: apply LN-all elementwise.  Y in slot 4p, Z written to slot 4p+1.
// grid (591, 3) block 256, float4 per thread.
// ---------------------------------------------------------------------------
__global__ __launch_bounds__(256) void k_lnall(
    float* __restrict__ wsbuf, const float* __restrict__ stats,
    const float* __restrict__ w0, const float* __restrict__ b0,
    const float* __restrict__ w1, const float* __restrict__ b1,
    const float* __restrict__ w2, const float* __restrict__ b2)
{
  const int p = blockIdx.y;
  const float* __restrict__ w = (p == 0) ? w0 : (p == 1) ? w1 : w2;
  const float* __restrict__ b = (p == 0) ? b0 : (p == 1) ? b1 : b2;
  const float mean = stats[p * 2 + 0];
  const float rstd = stats[p * 2 + 1];
  size_t i = ((size_t)blockIdx.x * 256 + threadIdx.x) * 4;
  const float* Yp = wsbuf + (size_t)(4 * p) * EN;
  float* Zp = wsbuf + (size_t)(4 * p + 1) * EN;
  float4 y = *(const float4*)(Yp + i);
  float4 wv = *(const float4*)(w + i);
  float4 bv = *(const float4*)(b + i);
  float4 zv;
  zv.x = (y.x - mean) * rstd * wv.x + bv.x;
  zv.y = (y.y - mean) * rstd * wv.y + bv.y;
  zv.z = (y.z - mean) * rstd * wv.z + bv.z;
  zv.w = (y.w - mean) * rstd * wv.w + bv.w;
  *(float4*)(Zp + i) = zv;
}

// ---------------------------------------------------------------------------
// Kernel 5: fused attention, 16 Q-rows per block, P kept in registers,
// PV reads P via __shfl broadcast.  grid (48, 13) block 256.
// O = softmax(QK^T*scale)V + V[s] (identity fold).
// ---------------------------------------------------------------------------
__global__ __launch_bounds__(256) void k_attn(
    const float* __restrict__ zq, const float* __restrict__ zk,
    const float* __restrict__ zv, float* __restrict__ obuf, float scale)
{
  const int bh = blockIdx.x, b = bh / H_, h = bh % H_;
  const int s0 = blockIdx.y * 16;

  __shared__ float Qs[16][68];    // [row][d]
  __shared__ float KVs[64][68];   // K phase: [d][t]; V phase: [t][d]

  const int tid = threadIdx.x;
  const int tx = tid & 15;        // t-slice (4 t per lane) / d-slice in PV
  const int ty = tid >> 4;        // row 0..15

  // stage Q: 16 rows x 64 d, 1 float4/thread
  {
    int sl = tid >> 4, c4 = (tid & 15) * 4;
    int s = s0 + sl;
    float4 v = make_float4(0.f, 0.f, 0.f, 0.f);
    if (s < S_) v = *(const float4*)(zq + (size_t)(b * S_ + s) * E_ + h * D_ + c4);
    *(float4*)(&Qs[sl][c4]) = v;
  }

  float accS[4][4];
  #pragma unroll
  for (int tt = 0; tt < 4; ++tt)
    #pragma unroll
    for (int j = 0; j < 4; ++j) accS[tt][j] = 0.f;

  // ---- QK^T phase: KVs = K tile [d][t] ----
  #pragma unroll
  for (int tt = 0; tt < 4; ++tt) {
    __syncthreads();   // prior KVs consumers done (covers Qs staging at tt=0)
    #pragma unroll
    for (int it = 0; it < 4; ++it) {
      int idx = tid + it * 256;
      int tl = idx >> 4, c4 = (idx & 15) * 4;
      int t = tt * 64 + tl;
      float4 u = make_float4(0.f, 0.f, 0.f, 0.f);
      if (t < S_) u = *(const float4*)(zk + (size_t)(b * S_ + t) * E_ + h * D_ + c4);
      KVs[c4 + 0][tl] = u.x; KVs[c4 + 1][tl] = u.y;
      KVs[c4 + 2][tl] = u.z; KVs[c4 + 3][tl] = u.w;
    }
    __syncthreads();
    #pragma unroll
    for (int dd = 0; dd < 16; ++dd) {
      float4 q4 = *(const float4*)(&Qs[ty][dd * 4]);
      float qa[4] = {q4.x, q4.y, q4.z, q4.w};
      #pragma unroll
      for (int k = 0; k < 4; ++k) {
        float4 k4 = *(const float4*)(&KVs[dd * 4 + k][tx * 4]);
        accS[tt][0] += qa[k] * k4.x;
        accS[tt][1] += qa[k] * k4.y;
        accS[tt][2] += qa[k] * k4.z;
        accS[tt][3] += qa[k] * k4.w;
      }
    }
  }

  // ---- softmax over the row (spread across the 16-lane tx group) ----
  float m = -1e30f;
  #pragma unroll
  for (int tt = 0; tt < 4; ++tt)
    #pragma unroll
    for (int j = 0; j < 4; ++j) {
      int t = tt * 64 + tx * 4 + j;
      float v = (t < S_) ? accS[tt][j] * scale : -1e30f;
      accS[tt][j] = v;
      m = fmaxf(m, v);
    }
  #pragma unroll
  for (int off = 1; off < 16; off <<= 1) m = fmaxf(m, __shfl_xor(m, off, 16));
  float sum = 0.f;
  #pragma unroll
  for (int tt = 0; tt < 4; ++tt)
    #pragma unroll
    for (int j = 0; j < 4; ++j) {
      float pv = __expf(accS[tt][j] - m);   // exp(-huge) = 0 for invalid t
      accS[tt][j] = pv;
      sum += pv;
    }
  #pragma unroll
  for (int off = 1; off < 16; off <<= 1) sum += __shfl_xor(sum, off, 16);
  const float inv = 1.f / sum;

  // ---- PV phase: KVs = V tile [t][d]; P broadcast via shfl ----
  float accO[4] = {0.f, 0.f, 0.f, 0.f};
  #pragma unroll
  for (int tt = 0; tt < 4; ++tt) {
    __syncthreads();
    #pragma unroll
    for (int it = 0; it < 4; ++it) {
      int idx = tid + it * 256;
      int tl = idx >> 4, c4 = (idx & 15) * 4;
      int t = tt * 64 + tl;
      float4 u = make_float4(0.f, 0.f, 0.f, 0.f);
      if (t < S_) u = *(const float4*)(zv + (size_t)(b * S_ + t) * E_ + h * D_ + c4);
      *(float4*)(&KVs[tl][c4]) = u;
    }
    __syncthreads();
    #pragma unroll 8
    for (int tl = 0; tl < 64; ++tl) {
      float pp = __shfl(accS[tt][tl & 3], ((ty & 3) << 4) | (tl >> 2), 64);
      float4 v4 = *(const float4*)(&KVs[tl][tx * 4]);
      accO[0] += pp * v4.x;
      accO[1] += pp * v4.y;
      accO[2] += pp * v4.z;
      accO[3] += pp * v4.w;
    }
  }

  // epilogue: O = O*inv + V[s]  (identity fold)
  const int s = s0 + ty;
  if (s < S_) {
    float4 vs = *(const float4*)(zv + (size_t)(b * S_ + s) * E_ + h * D_ + tx * 4);
    float4 o;
    o.x = accO[0] * inv + vs.x;
    o.y = accO[1] * inv + vs.y;
    o.z = accO[2] * inv + vs.z;
    o.w = accO[3] * inv + vs.w;
    *(float4*)(obuf + (size_t)(b * S_ + s) * E_ + h * D_ + tx * 4) = o;
  }
}

// ---------------------------------------------------------------------------
// Kernel 6: LayerNorm over last dim (E) per token row. grid(394) block 256.
// ---------------------------------------------------------------------------
__global__ __launch_bounds__(256) void k_lnlast(
    const float* __restrict__ obuf,
    const float* __restrict__ lw, const float* __restrict__ lb,
    float* __restrict__ oln)
{
  const int row = blockIdx.x * 4 + (threadIdx.x >> 6);
  const int lane = threadIdx.x & 63;
  const float* base = obuf + (size_t)row * E_;
  float v[6];
  float s1 = 0.f;
  #pragma unroll
  for (int j = 0; j < 6; ++j) { v[j] = base[lane + 64 * j]; s1 += v[j]; }
  #pragma unroll
  for (int off = 32; off > 0; off >>= 1) s1 += __shfl_xor(s1, off);
  float mean = s1 * (1.f / E_);
  float s2 = 0.f;
  #pragma unroll
  for (int j = 0; j < 6; ++j) { float d = v[j] - mean; s2 += d * d; }
  #pragma unroll
  for (int off = 32; off > 0; off >>= 1) s2 += __shfl_xor(s2, off);
  float rstd = rsqrtf(s2 * (1.f / E_) + 1e-5f);
  float* ob = oln + (size_t)row * E_;
  #pragma unroll
  for (int j = 0; j < 6; ++j) {
    int e = lane + 64 * j;
    ob[e] = (v[j] - mean) * rstd * lw[e] + lb[e];
  }
}

// ---------------------------------------------------------------------------
// Kernel 7: final GEMM  out[n][j] = sum_e oln[n][e]*fcw[j][e] + fcb[j]
// Tile 64j x 32n, thread 4j x 2n.  grid (6, 50) block 256.
// ---------------------------------------------------------------------------
__global__ __launch_bounds__(256) void k_fc(
    const float* __restrict__ oln, const float* __restrict__ fcw,
    const float* __restrict__ fcb, float* __restrict__ out)
{
  const int j0 = blockIdx.x * 64, n0 = blockIdx.y * 32;
  __shared__ float Xs[16][36];   // [e][n]
  __shared__ float Ws[16][68];   // [e][j]
  const int tid = threadIdx.x;
  const int tx = tid & 15, ty = tid >> 4;
  float acc[4][2];
  #pragma unroll
  for (int i = 0; i < 4; ++i) { acc[i][0] = 0.f; acc[i][1] = 0.f; }

  for (int e0 = 0; e0 < E_; e0 += 16) {
    {
      // X tile: 32 n x 16 e, float2/thread, transposed into Xs[e][n]
      int nl = tid >> 3, e2 = (tid & 7) * 2;
      int n = n0 + nl;
      float2 v = make_float2(0.f, 0.f);
      if (n < N_) v = *(const float2*)(oln + (size_t)n * E_ + e0 + e2);
      Xs[e2 + 0][nl] = v.x; Xs[e2 + 1][nl] = v.y;
      // W tile: 64 j x 16 e, float4/thread, transposed into Ws[e][j]
      int jl = tid >> 2, c4 = (tid & 3) * 4;
      float4 u = *(const float4*)(fcw + (size_t)(j0 + jl) * E_ + e0 + c4);
      Ws[c4 + 0][jl] = u.x; Ws[c4 + 1][jl] = u.y;
      Ws[c4 + 2][jl] = u.z; Ws[c4 + 3][jl] = u.w;
    }
    __syncthreads();
    #pragma unroll
    for (int cc = 0; cc < 16; ++cc) {
      float2 x2 = *(const float2*)(&Xs[cc][tx * 2]);
      float4 w4 = *(const float4*)(&Ws[cc][ty * 4]);
      float xa[2] = {x2.x, x2.y};
      float wa[4] = {w4.x, w4.y, w4.z, w4.w};
      #pragma unroll
      for (int i = 0; i < 4; ++i) {
        acc[i][0] += wa[i] * xa[0];
        acc[i][1] += wa[i] * xa[1];
      }
    }
    __syncthreads();
  }
  const int jc = j0 + ty * 4;
  float4 bv = *(const float4*)(fcb + jc);
  #pragma unroll
  for (int jn = 0; jn < 2; ++jn) {
    int n = n0 + tx * 2 + jn;
    if (n < N_) {
      float4 o;
      o.x = acc[0][jn] + bv.x;
      o.y = acc[1][jn] + bv.y;
      o.z = acc[2][jn] + bv.z;
      o.w = acc[3][jn] + bv.w;
      *(float4*)(out + (size_t)n * E_ + jc) = o;
    }
  }
}

// ---------------------------------------------------------------------------
extern "C" void kernel_launch(void* const* d_in, const int* in_sizes, int n_in,
                              void* d_out, int out_size, void* d_ws, size_t ws_size,
                              hipStream_t stream)
{
  const float* x   = (const float*)d_in[0];
  const float* wq  = (const float*)d_in[1];
  const float* wk  = (const float*)d_in[2];
  const float* wv  = (const float*)d_in[3];
  const float* qw  = (const float*)d_in[4];
  const float* qb  = (const float*)d_in[5];
  const float* kw  = (const float*)d_in[6];
  const float* kb  = (const float*)d_in[7];
  const float* vw  = (const float*)d_in[8];
  const float* vb  = (const float*)d_in[9];
  const float* ow  = (const float*)d_in[10];
  const float* obp = (const float*)d_in[11];
  const float* fcw = (const float*)d_in[12];
  const float* fcb = (const float*)d_in[13];
  float* out = (float*)d_out;
  float* ws  = (float*)d_ws;

  // ws layout (floats): slots 0..11 = adder partials [4p+c].
  // After reduce: slot 4p = Y_p.  After lnall: slot 4p+1 = Z_p.
  // After lnall all Y slots are dead: obuf = slot 0, oln = slot 2.
  float* obuf  = ws + 0 * EN;
  float* oln   = ws + 2 * EN;
  float* part  = ws + 12 * EN;                 // 3*591*2
  float* stats = part + 3 * NBLK_RED * 2;      // 6

  const float scale = (float)pow(2.0 * D_ * (1.0 - 2.0 / M_PI), -0.5);

  k_adder<<<dim3(6, 25, 12), 256, 0, stream>>>(x, wq, wk, wv, ws);
  k_reduceY<<<dim3(NBLK_RED, 3), 256, 0, stream>>>(ws, part);
  k_stats<<<dim3(3), 256, 0, stream>>>(part, stats);
  k_lnall<<<dim3(NBLK_RED, 3), 256, 0, stream>>>(ws, stats, qw, qb, kw, kb, vw, vb);
  const float* zq = ws + 1 * EN;
  const float* zk = ws + 5 * EN;
  const float* zv = ws + 9 * EN;
  k_attn<<<dim3(48, 13), 256, 0, stream>>>(zq, zk, zv, obuf, scale);
  k_lnlast<<<dim3(394), 256, 0, stream>>>(obuf, ow, obp, oln);
  k_fc<<<dim3(6, 50), 256, 0, stream>>>(oln, fcw, fcb, out);
}

// Round 5
// 113.745 us; speedup vs baseline: 2.3649x; 2.3649x over previous
//
#include <hip/hip_runtime.h>
#include <math.h>

#ifndef M_PI
#define M_PI 3.14159265358979323846
#endif

#define B_ 8
#define S_ 197
#define E_ 384
#define H_ 6
#define D_ 64
#define N_ (B_*S_)          // 1576
#define EN ((size_t)E_*N_)  // 605184
#define NBLK_RED 591        // EN / 1024 exactly

// ---------------------------------------------------------------------------
// Kernel 1: adder 1x1 partials, split-K over ci (4 chunks of 96).
// P[z][co][n] = sum_{ci in chunk} |x2d[ci][n] - w[co][ci]|,  z = 4p + c.
// Tile 64co x 64n, thread = 4co x 4n.  grid (6, 25, 12) block 256.
// Double-buffered LDS, one barrier per 16-ci step.
// ---------------------------------------------------------------------------
__global__ __launch_bounds__(256) void k_adder(
    const float* __restrict__ x,
    const float* __restrict__ wq, const float* __restrict__ wk,
    const float* __restrict__ wv,
    float* __restrict__ P)
{
  const int z = blockIdx.z;
  const int p = z >> 2, c = z & 3;
  const float* __restrict__ w = (p == 0) ? wq : (p == 1) ? wk : wv;
  const int co0 = blockIdx.x * 64;
  const int n0  = blockIdx.y * 64;
  const int cib = c * 96;

  __shared__ float Xs[2][16][68];   // [buf][ci_local][n_local]
  __shared__ float Ws[2][16][68];   // [buf][ci_local][co_local] (transposed)

  const int tid = threadIdx.x;
  const int tx = tid & 15;          // n direction (4 cols)
  const int ty = tid >> 4;          // co direction (4 rows)

  const int xr = tid >> 4, xc = (tid & 15) * 4;   // X stage: [16][64] float4
  const int wr = tid >> 2, wc = (tid & 3) * 4;    // W stage: 64co x 16ci float4

  const bool xok = (n0 + xc + 3) < N_;            // full float4 or none
  const float* xg = x + (size_t)(cib + xr) * N_ + n0 + xc;
  const float* wg = w + (size_t)(co0 + wr) * E_ + cib + wc;

  float4 xv = xok ? *(const float4*)xg : make_float4(0.f, 0.f, 0.f, 0.f);
  float4 wv4 = *(const float4*)wg;

  float acc[4][4];
  #pragma unroll
  for (int i = 0; i < 4; ++i)
    #pragma unroll
    for (int j = 0; j < 4; ++j) acc[i][j] = 0.f;

  #pragma unroll 1
  for (int t = 0; t < 6; ++t) {
    const int buf = t & 1;
    *(float4*)(&Xs[buf][xr][xc]) = xv;
    Ws[buf][wc + 0][wr] = wv4.x; Ws[buf][wc + 1][wr] = wv4.y;
    Ws[buf][wc + 2][wr] = wv4.z; Ws[buf][wc + 3][wr] = wv4.w;
    __syncthreads();
    if (t < 5) {
      xg += (size_t)16 * N_;
      wg += 16;
      xv = xok ? *(const float4*)xg : make_float4(0.f, 0.f, 0.f, 0.f);
      wv4 = *(const float4*)wg;
    }
    #pragma unroll
    for (int cc = 0; cc < 16; ++cc) {
      float4 a = *(const float4*)(&Xs[buf][cc][tx * 4]);
      float4 b = *(const float4*)(&Ws[buf][cc][ty * 4]);
      float xa[4] = {a.x, a.y, a.z, a.w};
      float wa[4] = {b.x, b.y, b.z, b.w};
      #pragma unroll
      for (int i = 0; i < 4; ++i)
        #pragma unroll
        for (int j = 0; j < 4; ++j)
          acc[i][j] += fabsf(xa[j] - wa[i]);
    }
  }

  if ((n0 + tx * 4 + 3) < N_) {
    #pragma unroll
    for (int i = 0; i < 4; ++i) {
      int co = co0 + ty * 4 + i;
      float4 yv = make_float4(acc[i][0], acc[i][1], acc[i][2], acc[i][3]);
      *(float4*)(P + (size_t)z * EN + (size_t)co * N_ + n0 + tx * 4) = yv;
    }
  }
}

// ---------------------------------------------------------------------------
// Kernel 2: reduce split-K partials in place: Y(=slot 4p) = -(P0+P1+P2+P3),
// plus per-block (sum, sumsq) partials for LN-all.  grid (591, 3) block 256.
// ---------------------------------------------------------------------------
__global__ __launch_bounds__(256) void k_reduceY(
    float* __restrict__ wsbuf, float* __restrict__ partials)
{
  const int p = blockIdx.y;
  float* P0 = wsbuf + (size_t)(4 * p) * EN;
  const int tid = threadIdx.x;
  size_t i = ((size_t)blockIdx.x * 256 + tid) * 4;
  float4 a = *(const float4*)(P0 + i);
  float4 b = *(const float4*)(P0 + EN + i);
  float4 cc = *(const float4*)(P0 + 2 * EN + i);
  float4 d = *(const float4*)(P0 + 3 * EN + i);
  float4 y;
  y.x = -(a.x + b.x + cc.x + d.x);
  y.y = -(a.y + b.y + cc.y + d.y);
  y.z = -(a.z + b.z + cc.z + d.z);
  y.w = -(a.w + b.w + cc.w + d.w);
  *(float4*)(P0 + i) = y;
  float s1 = y.x + y.y + y.z + y.w;
  float s2 = y.x * y.x + y.y * y.y + y.z * y.z + y.w * y.w;
  #pragma unroll
  for (int off = 32; off > 0; off >>= 1) {
    s1 += __shfl_down(s1, off);
    s2 += __shfl_down(s2, off);
  }
  __shared__ float red[8];
  int wid = tid >> 6, lane = tid & 63;
  if (lane == 0) { red[wid * 2] = s1; red[wid * 2 + 1] = s2; }
  __syncthreads();
  if (tid == 0) {
    float t1 = red[0] + red[2] + red[4] + red[6];
    float t2 = red[1] + red[3] + red[5] + red[7];
    partials[((size_t)p * NBLK_RED + blockIdx.x) * 2 + 0] = t1;
    partials[((size_t)p * NBLK_RED + blockIdx.x) * 2 + 1] = t2;
  }
}

// ---------------------------------------------------------------------------
// Kernel 3: reduce partials -> (mean, rstd) per projection.  grid(3) block 256
// ---------------------------------------------------------------------------
__global__ __launch_bounds__(256) void k_stats(
    const float* __restrict__ partials, float* __restrict__ stats)
{
  const int p = blockIdx.x;
  const int tid = threadIdx.x;
  float s1 = 0.f, s2 = 0.f;
  for (int i = tid; i < NBLK_RED; i += 256) {
    s1 += partials[((size_t)p * NBLK_RED + i) * 2 + 0];
    s2 += partials[((size_t)p * NBLK_RED + i) * 2 + 1];
  }
  #pragma unroll
  for (int off = 32; off > 0; off >>= 1) {
    s1 += __shfl_down(s1, off);
    s2 += __shfl_down(s2, off);
  }
  __shared__ float red[8];
  int wid = tid >> 6, lane = tid & 63;
  if (lane == 0) { red[wid * 2] = s1; red[wid * 2 + 1] = s2; }
  __syncthreads();
  if (tid == 0) {
    float S1 = red[0] + red[2] + red[4] + red[6];
    float S2 = red[1] + red[3] + red[5] + red[7];
    float mean = S1 / (float)EN;
    float var = S2 / (float)EN - mean * mean;
    stats[p * 2 + 0] = mean;
    stats[p * 2 + 1] = rsqrtf(var + 1e-5f);
  }
}

// ---------------------------------------------------------------------------
// Kernel 4: apply LN-all elementwise.  Y in slot 4p, Z written to slot 4p+1.
// grid (591, 3) block 256, float4 per thread.
// ---------------------------------------------------------------------------
__global__ __launch_bounds__(256) void k_lnall(
    float* __restrict__ wsbuf, const float* __restrict__ stats,
    const float* __restrict__ w0, const float* __restrict__ b0,
    const float* __restrict__ w1, const float* __restrict__ b1,
    const float* __restrict__ w2, const float* __restrict__ b2)
{
  const int p = blockIdx.y;
  const float* __restrict__ w = (p == 0) ? w0 : (p == 1) ? w1 : w2;
  const float* __restrict__ b = (p == 0) ? b0 : (p == 1) ? b1 : b2;
  const float mean = stats[p * 2 + 0];
  const float rstd = stats[p * 2 + 1];
  size_t i = ((size_t)blockIdx.x * 256 + threadIdx.x) * 4;
  const float* Yp = wsbuf + (size_t)(4 * p) * EN;
  float* Zp = wsbuf + (size_t)(4 * p + 1) * EN;
  float4 y = *(const float4*)(Yp + i);
  float4 wv = *(const float4*)(w + i);
  float4 bv = *(const float4*)(b + i);
  float4 zv;
  zv.x = (y.x - mean) * rstd * wv.x + bv.x;
  zv.y = (y.y - mean) * rstd * wv.y + bv.y;
  zv.z = (y.z - mean) * rstd * wv.z + bv.z;
  zv.w = (y.w - mean) * rstd * wv.w + bv.w;
  *(float4*)(Zp + i) = zv;
}

// ---------------------------------------------------------------------------
// Kernel 5: fused attention: scores + softmax + (P+I)V  per (bh, 32-row tile).
// grid (48, 7) block 256.  O += V[s] folds the +eye(S).
// (R3-proven version: Ps staged in LDS, all register indexing static.)
// ---------------------------------------------------------------------------
__global__ __launch_bounds__(256) void k_attn(
    const float* __restrict__ zq, const float* __restrict__ zk,
    const float* __restrict__ zv, float* __restrict__ obuf, float scale)
{
  const int bh = blockIdx.x, b = bh / H_, h = bh % H_;
  const int s0 = blockIdx.y * 32;

  __shared__ float Qs[64][36];    // [d][s_local]
  __shared__ float KVs[64][68];   // K phase: [d][t_local]; V phase: [t_local][d]
  __shared__ float Ps[32][200];   // unnormalized exp scores
  __shared__ float linv[32];

  const int tid = threadIdx.x;
  const int tx = tid & 15, ty = tid >> 4;

  // stage Q: 32 rows x 64 d -> Qs[d][s]
  #pragma unroll
  for (int it = 0; it < 2; ++it) {
    int idx = tid + it * 256;
    int sl = idx >> 4, c4 = (idx & 15) * 4;
    int s = s0 + sl;
    float4 v = make_float4(0.f, 0.f, 0.f, 0.f);
    if (s < S_) v = *(const float4*)(zq + (size_t)(b * S_ + s) * E_ + h * D_ + c4);
    Qs[c4 + 0][sl] = v.x; Qs[c4 + 1][sl] = v.y;
    Qs[c4 + 2][sl] = v.z; Qs[c4 + 3][sl] = v.w;
  }

  float accS[4][2][4];
  #pragma unroll
  for (int tt = 0; tt < 4; ++tt)
    #pragma unroll
    for (int r = 0; r < 2; ++r)
      #pragma unroll
      for (int j = 0; j < 4; ++j) accS[tt][r][j] = 0.f;

  #pragma unroll
  for (int tt = 0; tt < 4; ++tt) {
    __syncthreads();   // previous KVs consumers done (also covers Qs staging)
    #pragma unroll
    for (int it = 0; it < 4; ++it) {
      int idx = tid + it * 256;
      int tl = idx >> 4, c4 = (idx & 15) * 4;
      int t = tt * 64 + tl;
      float4 u = make_float4(0.f, 0.f, 0.f, 0.f);
      if (t < S_) u = *(const float4*)(zk + (size_t)(b * S_ + t) * E_ + h * D_ + c4);
      KVs[c4 + 0][tl] = u.x; KVs[c4 + 1][tl] = u.y;
      KVs[c4 + 2][tl] = u.z; KVs[c4 + 3][tl] = u.w;
    }
    __syncthreads();
    #pragma unroll 8
    for (int d = 0; d < 64; ++d) {
      float2 q2 = *(const float2*)(&Qs[d][2 * ty]);
      float4 k4 = *(const float4*)(&KVs[d][tx * 4]);
      float ka[4] = {k4.x, k4.y, k4.z, k4.w};
      #pragma unroll
      for (int j = 0; j < 4; ++j) {
        accS[tt][0][j] += q2.x * ka[j];
        accS[tt][1][j] += q2.y * ka[j];
      }
    }
  }

  // row softmax over full 197 (rows 2ty, 2ty+1; cols spread over 16 tx lanes)
  float mr0 = -1e30f, mr1 = -1e30f;
  #pragma unroll
  for (int tt = 0; tt < 4; ++tt)
    #pragma unroll
    for (int j = 0; j < 4; ++j) {
      int t = tt * 64 + tx * 4 + j;
      float v0 = (t < S_) ? accS[tt][0][j] * scale : -1e30f;
      float v1 = (t < S_) ? accS[tt][1][j] * scale : -1e30f;
      accS[tt][0][j] = v0; accS[tt][1][j] = v1;
      mr0 = fmaxf(mr0, v0); mr1 = fmaxf(mr1, v1);
    }
  #pragma unroll
  for (int off = 1; off < 16; off <<= 1) {
    mr0 = fmaxf(mr0, __shfl_xor(mr0, off));
    mr1 = fmaxf(mr1, __shfl_xor(mr1, off));
  }
  float sr0 = 0.f, sr1 = 0.f;
  #pragma unroll
  for (int tt = 0; tt < 4; ++tt)
    #pragma unroll
    for (int j = 0; j < 4; ++j) {
      float p0 = __expf(accS[tt][0][j] - mr0);
      float p1 = __expf(accS[tt][1][j] - mr1);
      accS[tt][0][j] = p0; accS[tt][1][j] = p1;
      sr0 += p0; sr1 += p1;
    }
  #pragma unroll
  for (int off = 1; off < 16; off <<= 1) {
    sr0 += __shfl_xor(sr0, off);
    sr1 += __shfl_xor(sr1, off);
  }
  if (tx == 0) { linv[2 * ty] = 1.f / sr0; linv[2 * ty + 1] = 1.f / sr1; }
  #pragma unroll
  for (int tt = 0; tt < 4; ++tt) {
    int t4 = tt * 64 + tx * 4;
    if (t4 < 200) {
      *(float4*)(&Ps[2 * ty][t4]) =
          make_float4(accS[tt][0][0], accS[tt][0][1], accS[tt][0][2], accS[tt][0][3]);
      *(float4*)(&Ps[2 * ty + 1][t4]) =
          make_float4(accS[tt][1][0], accS[tt][1][1], accS[tt][1][2], accS[tt][1][3]);
    }
  }

  // PV phase: O[2 rows][4 d] per thread
  float accO[2][4];
  #pragma unroll
  for (int r = 0; r < 2; ++r)
    #pragma unroll
    for (int j = 0; j < 4; ++j) accO[r][j] = 0.f;

  #pragma unroll
  for (int tt = 0; tt < 4; ++tt) {
    __syncthreads();   // S-phase/previous-PV KVs reads done; Ps visible (tt=0)
    #pragma unroll
    for (int it = 0; it < 4; ++it) {
      int idx = tid + it * 256;
      int tl = idx >> 4, c4 = (idx & 15) * 4;
      int t = tt * 64 + tl;
      float4 u = make_float4(0.f, 0.f, 0.f, 0.f);
      if (t < S_) u = *(const float4*)(zv + (size_t)(b * S_ + t) * E_ + h * D_ + c4);
      *(float4*)(&KVs[tl][c4]) = u;
    }
    __syncthreads();
    const int tmax = (tt < 3) ? 64 : 8;   // Ps cols < 200
    #pragma unroll 8
    for (int tl = 0; tl < tmax; ++tl) {
      float p0 = Ps[2 * ty][tt * 64 + tl];
      float p1 = Ps[2 * ty + 1][tt * 64 + tl];
      float4 v4 = *(const float4*)(&KVs[tl][tx * 4]);
      float va[4] = {v4.x, v4.y, v4.z, v4.w};
      #pragma unroll
      for (int j = 0; j < 4; ++j) {
        accO[0][j] += p0 * va[j];
        accO[1][j] += p1 * va[j];
      }
    }
  }

  // epilogue: O = O*inv + V[s]  (identity fold), store to obuf [B,S,E]
  #pragma unroll
  for (int r = 0; r < 2; ++r) {
    int s = s0 + 2 * ty + r;
    if (s < S_) {
      float inv = linv[2 * ty + r];
      float4 vs = *(const float4*)(zv + (size_t)(b * S_ + s) * E_ + h * D_ + tx * 4);
      float4 o;
      o.x = accO[r][0] * inv + vs.x;
      o.y = accO[r][1] * inv + vs.y;
      o.z = accO[r][2] * inv + vs.z;
      o.w = accO[r][3] * inv + vs.w;
      *(float4*)(obuf + (size_t)(b * S_ + s) * E_ + h * D_ + tx * 4) = o;
    }
  }
}

// ---------------------------------------------------------------------------
// Kernel 6: LayerNorm over last dim (E) per token row. grid(394) block 256.
// ---------------------------------------------------------------------------
__global__ __launch_bounds__(256) void k_lnlast(
    const float* __restrict__ obuf,
    const float* __restrict__ lw, const float* __restrict__ lb,
    float* __restrict__ oln)
{
  const int row = blockIdx.x * 4 + (threadIdx.x >> 6);
  const int lane = threadIdx.x & 63;
  const float* base = obuf + (size_t)row * E_;
  float v[6];
  float s1 = 0.f;
  #pragma unroll
  for (int j = 0; j < 6; ++j) { v[j] = base[lane + 64 * j]; s1 += v[j]; }
  #pragma unroll
  for (int off = 32; off > 0; off >>= 1) s1 += __shfl_xor(s1, off);
  float mean = s1 * (1.f / E_);
  float s2 = 0.f;
  #pragma unroll
  for (int j = 0; j < 6; ++j) { float d = v[j] - mean; s2 += d * d; }
  #pragma unroll
  for (int off = 32; off > 0; off >>= 1) s2 += __shfl_xor(s2, off);
  float rstd = rsqrtf(s2 * (1.f / E_) + 1e-5f);
  float* ob = oln + (size_t)row * E_;
  #pragma unroll
  for (int j = 0; j < 6; ++j) {
    int e = lane + 64 * j;
    ob[e] = (v[j] - mean) * rstd * lw[e] + lb[e];
  }
}

// ---------------------------------------------------------------------------
// Kernel 7: final GEMM  out[n][j] = sum_e oln[n][e]*fcw[j][e] + fcb[j]
// Tile 64j x 32n, thread 4j x 2n.  grid (6, 50) block 256.
// ---------------------------------------------------------------------------
__global__ __launch_bounds__(256) void k_fc(
    const float* __restrict__ oln, const float* __restrict__ fcw,
    const float* __restrict__ fcb, float* __restrict__ out)
{
  const int j0 = blockIdx.x * 64, n0 = blockIdx.y * 32;
  __shared__ float Xs[16][36];   // [e][n]
  __shared__ float Ws[16][68];   // [e][j]
  const int tid = threadIdx.x;
  const int tx = tid & 15, ty = tid >> 4;
  float acc[4][2];
  #pragma unroll
  for (int i = 0; i < 4; ++i) { acc[i][0] = 0.f; acc[i][1] = 0.f; }

  for (int e0 = 0; e0 < E_; e0 += 16) {
    {
      // X tile: 32 n x 16 e, float2/thread, transposed into Xs[e][n]
      int nl = tid >> 3, e2 = (tid & 7) * 2;
      int n = n0 + nl;
      float2 v = make_float2(0.f, 0.f);
      if (n < N_) v = *(const float2*)(oln + (size_t)n * E_ + e0 + e2);
      Xs[e2 + 0][nl] = v.x; Xs[e2 + 1][nl] = v.y;
      // W tile: 64 j x 16 e, float4/thread, transposed into Ws[e][j]
      int jl = tid >> 2, c4 = (tid & 3) * 4;
      float4 u = *(const float4*)(fcw + (size_t)(j0 + jl) * E_ + e0 + c4);
      Ws[c4 + 0][jl] = u.x; Ws[c4 + 1][jl] = u.y;
      Ws[c4 + 2][jl] = u.z; Ws[c4 + 3][jl] = u.w;
    }
    __syncthreads();
    #pragma unroll
    for (int cc = 0; cc < 16; ++cc) {
      float2 x2 = *(const float2*)(&Xs[cc][tx * 2]);
      float4 w4 = *(const float4*)(&Ws[cc][ty * 4]);
      float xa[2] = {x2.x, x2.y};
      float wa[4] = {w4.x, w4.y, w4.z, w4.w};
      #pragma unroll
      for (int i = 0; i < 4; ++i) {
        acc[i][0] += wa[i] * xa[0];
        acc[i][1] += wa[i] * xa[1];
      }
    }
    __syncthreads();
  }
  const int jc = j0 + ty * 4;
  float4 bv = *(const float4*)(fcb + jc);
  #pragma unroll
  for (int jn = 0; jn < 2; ++jn) {
    int n = n0 + tx * 2 + jn;
    if (n < N_) {
      float4 o;
      o.x = acc[0][jn] + bv.x;
      o.y = acc[1][jn] + bv.y;
      o.z = acc[2][jn] + bv.z;
      o.w = acc[3][jn] + bv.w;
      *(float4*)(out + (size_t)n * E_ + jc) = o;
    }
  }
}

// ---------------------------------------------------------------------------
extern "C" void kernel_launch(void* const* d_in, const int* in_sizes, int n_in,
                              void* d_out, int out_size, void* d_ws, size_t ws_size,
                              hipStream_t stream)
{
  const float* x   = (const float*)d_in[0];
  const float* wq  = (const float*)d_in[1];
  const float* wk  = (const float*)d_in[2];
  const float* wv  = (const float*)d_in[3];
  const float* qw  = (const float*)d_in[4];
  const float* qb  = (const float*)d_in[5];
  const float* kw  = (const float*)d_in[6];
  const float* kb  = (const float*)d_in[7];
  const float* vw  = (const float*)d_in[8];
  const float* vb  = (const float*)d_in[9];
  const float* ow  = (const float*)d_in[10];
  const float* obp = (const float*)d_in[11];
  const float* fcw = (const float*)d_in[12];
  const float* fcb = (const float*)d_in[13];
  float* out = (float*)d_out;
  float* ws  = (float*)d_ws;

  // ws layout (floats): slots 0..11 = adder partials [4p+c].
  // After reduce: slot 4p = Y_p.  After lnall: slot 4p+1 = Z_p.
  // After lnall all Y slots are dead: obuf = slot 0, oln = slot 2.
  float* obuf  = ws + 0 * EN;
  float* oln   = ws + 2 * EN;
  float* part  = ws + 12 * EN;                 // 3*591*2
  float* stats = part + 3 * NBLK_RED * 2;      // 6

  const float scale = (float)pow(2.0 * D_ * (1.0 - 2.0 / M_PI), -0.5);

  k_adder<<<dim3(6, 25, 12), 256, 0, stream>>>(x, wq, wk, wv, ws);
  k_reduceY<<<dim3(NBLK_RED, 3), 256, 0, stream>>>(ws, part);
  k_stats<<<dim3(3), 256, 0, stream>>>(part, stats);
  k_lnall<<<dim3(NBLK_RED, 3), 256, 0, stream>>>(ws, stats, qw, qb, kw, kb, vw, vb);
  const float* zq = ws + 1 * EN;
  const float* zk = ws + 5 * EN;
  const float* zv = ws + 9 * EN;
  k_attn<<<dim3(48, 7), 256, 0, stream>>>(zq, zk, zv, obuf, scale);
  k_lnlast<<<dim3(394), 256, 0, stream>>>(obuf, ow, obp, oln);
  k_fc<<<dim3(6, 50), 256, 0, stream>>>(oln, fcw, fcb, out);
}